// Round 5
// baseline (142.360 us; speedup 1.0000x reference)
//
#include <hip/hip_runtime.h>

// Terrain3D — gather formulation, chunked LDS tables for full occupancy.
// ws layout (floats): [0, 5*G3) = H,E grids; then int counts[NTILES];
// then int lists[NTILES*CAP]; then float4 meta[2*N] ({gx,gy,gz,omega},{m0..m3}).

namespace {
constexpr int   G      = 128;
constexpr int   G3     = G * G * G;
constexpr int   NE     = 4;
constexpr int   RAD    = 9;            // max(2, int(3*0.05*128/2)) = 9
constexpr float SIG    = 0.05f * (float)G * 0.5f;  // 3.2
constexpr float INV2S2 = 1.0f / (2.0f * SIG * SIG);
constexpr float ETA    = 0.01f;
constexpr float A_H    = 0.002f;
constexpr float A_E    = 0.001f;
constexpr float LEAK   = 5e-5f;

// tile geometry: 4 x 8 x 32 voxels (axis2 fastest in memory). 256 threads,
// each owning the full 4-voxel axis0 stripe at its (j,k).
constexpr int T0 = 4, T1 = 8, T2 = 32;
constexpr int NT0 = G / T0, NT1 = G / T1, NT2 = G / T2;   // 32, 16, 4
constexpr int NTILES = NT0 * NT1 * NT2;                   // 2048
constexpr int CAP = 128;   // mean particles/tile ~67; max over tiles ~100
constexpr int CHUNK = 32;  // particles per LDS table chunk (6144 B tables)
}

__device__ __forceinline__ int clampi(int v, int lo, int hi) {
    return min(max(v, lo), hi);
}

// ---------------------------------------------------------------------------
// 0) zero the tile counts (replaces hipMemsetAsync fill dispatch)
// ---------------------------------------------------------------------------
__global__ void zero_counts(int4* __restrict__ counts4) {
    counts4[threadIdx.x + blockIdx.x * blockDim.x] = make_int4(0, 0, 0, 0);
}

// ---------------------------------------------------------------------------
// 1) bin + meta: one WAVE per particle. Lane 0 writes particle meta; the
//    first 48 lanes cover the 6x4x2 candidate-tile grid of the bbox.
// ---------------------------------------------------------------------------
__global__ void __launch_bounds__(256) bin_meta_kernel(
        const float* __restrict__ pos, const float* __restrict__ inten,
        const float4* __restrict__ emo4,
        int* __restrict__ counts, int* __restrict__ lists,
        float4* __restrict__ meta, int N) {
    const int p    = blockIdx.x * 4 + (threadIdx.x >> 6);
    const int lane = threadIdx.x & 63;
    if (p >= N) return;

    const float gx = (pos[p * 3 + 0] + 1.0f) * 0.5f * (float)(G - 1);
    const float gy = (pos[p * 3 + 1] + 1.0f) * 0.5f * (float)(G - 1);
    const float gz = (pos[p * 3 + 2] + 1.0f) * 0.5f * (float)(G - 1);
    const int c0 = clampi((int)floorf(gx), 0, G - 1);
    const int c1 = clampi((int)floorf(gy), 0, G - 1);
    const int c2 = clampi((int)floorf(gz), 0, G - 1);

    if (lane == 0) {
        meta[2 * p]     = make_float4(gx, gy, gz, inten[p] * ETA);
        meta[2 * p + 1] = emo4[p];
    }

    const int l0 = max(c0 - RAD, 0) >> 2, h0 = min(c0 + RAD, G - 1) >> 2;
    const int l1 = max(c1 - RAD, 0) >> 3, h1 = min(c1 + RAD, G - 1) >> 3;
    const int l2 = max(c2 - RAD, 0) >> 5, h2 = min(c2 + RAD, G - 1) >> 5;
    const int n0 = h0 - l0, n1 = h1 - l1, n2 = h2 - l2;  // inclusive spans - 1

    if (lane < 48) {                    // fixed 6x4x2 slot grid, single pass
        const int a  = lane >> 3;       // 0..5
        const int r  = lane & 7;
        const int b  = r >> 1;          // 0..3
        const int cs = r & 1;           // 0..1
        if (a <= n0 && b <= n1 && cs <= n2) {
            const int t = ((l0 + a) * NT1 + (l1 + b)) * NT2 + (l2 + cs);
            const int slot = atomicAdd(&counts[t], 1);
            if (slot < CAP) lists[t * CAP + slot] = p;
        }
    }
}

// ---------------------------------------------------------------------------
// 2) gather: one block per tile. Per CHUNK of particles, build tables in LDS
//    (kx[4] w/ omega folded + validity zeros, ky[8], kz[32], em[4] — 6144 B
//    total -> 8 blocks/CU), then hot loop is pure LDS + VALU:
//    2x ds_read_b128 broadcast + 2x ds_read_b32 + ~25 VALU for 20 accums.
// ---------------------------------------------------------------------------
__global__ void __launch_bounds__(256) gather_kernel(
        const float4* __restrict__ meta,
        const float* __restrict__ H0, const float* __restrict__ E0,
        const int* __restrict__ counts, const int* __restrict__ lists,
        float* __restrict__ ws) {
    const int tile = blockIdx.x;
    const int t2 = tile & 3, t1 = (tile >> 2) & 15, t0 = tile >> 6;
    const int tid = threadIdx.x;

    __shared__ __align__(16) float kxf[CHUNK * 4];
    __shared__ __align__(16) float emf[CHUNK * 4];
    __shared__ float ky[CHUNK * 8];
    __shared__ float kz[CHUNK * 32];

    const int cnt = min(counts[tile], CAP);
    const int* __restrict__ lst = lists + tile * CAP;

    const int b0 = t0 * T0, b1 = t1 * T1, b2 = t2 * T2;

    // ---- per-thread voxels: axis0 stripe i = 0..3 at (j, k) ----
    const int k = tid & 31;          // axis2
    const int j = tid >> 5;          // axis1, 0..7
    const int x2 = b2 + k, x1 = b1 + j;
    const int flat0 = (b0 * G + x1) * G + x2;   // i stride = G*G

    float h[4], e[NE][4];
#pragma unroll
    for (int i = 0; i < 4; ++i) {
        h[i] = H0[flat0 + i * G * G];
#pragma unroll
        for (int c = 0; c < NE; ++c) e[c][i] = E0[c * G3 + flat0 + i * G * G];
    }

    const float4* __restrict__ kx4 = (const float4*)kxf;
    const float4* __restrict__ em4 = (const float4*)emf;

    for (int base = 0; base < cnt; base += CHUNK) {
        const int m = min(CHUNK, cnt - base);
        __syncthreads();   // previous chunk fully consumed before overwrite

        // ---- build tables: 48 floats per particle (4 kx, 8 ky, 32 kz, 4 em)
        for (int t = tid; t < m * 48; t += 256) {
            const int n = t / 48;
            const int s = t - n * 48;
            const int p = lst[base + n];
            if (s < 44) {
                const float4 mg = meta[2 * p];
                const int axis = (s >= 4) + (s >= 12);
                const int off  = s - ((axis == 0) ? 0 : (axis == 1) ? 4 : 12);
                const float g  = (axis == 0) ? mg.x : (axis == 1) ? mg.y : mg.z;
                const int base3 = (axis == 0) ? b0 : (axis == 1) ? b1 : b2;
                const int cc    = clampi((int)floorf(g), 0, G - 1);
                const int coord = base3 + off;
                const float d = (float)coord - g;
                float v = (abs(coord - cc) <= RAD) ? __expf(-d * d * INV2S2) : 0.0f;
                if (axis == 0) {
                    kxf[n * 4 + off] = v * mg.w;     // fold omega into kx
                } else if (axis == 1) {
                    ky[n * 8 + off] = v;
                } else {
                    kz[n * 32 + off] = v;
                }
            } else {
                const float4 me = meta[2 * p + 1];
                const int q = s - 44;
                emf[n * 4 + q] = (q == 0) ? me.x : (q == 1) ? me.y
                               : (q == 2) ? me.z : me.w;
            }
        }
        __syncthreads();

        for (int n = 0; n < m; ++n) {
            const float4 kxv = kx4[n];               // ds_read_b128, broadcast
            const float4 emv = em4[n];               // ds_read_b128, broadcast
            const float kyz = ky[n * 8 + j] * kz[n * 32 + k];
            const float w0 = kxv.x * kyz, w1 = kxv.y * kyz;
            const float w2 = kxv.z * kyz, w3 = kxv.w * kyz;
            h[0] += w0;  h[1] += w1;  h[2] += w2;  h[3] += w3;
            e[0][0] += w0 * emv.x; e[0][1] += w1 * emv.x; e[0][2] += w2 * emv.x; e[0][3] += w3 * emv.x;
            e[1][0] += w0 * emv.y; e[1][1] += w1 * emv.y; e[1][2] += w2 * emv.y; e[1][3] += w3 * emv.y;
            e[2][0] += w0 * emv.z; e[2][1] += w1 * emv.z; e[2][2] += w2 * emv.z; e[2][3] += w3 * emv.z;
            e[3][0] += w0 * emv.w; e[3][1] += w1 * emv.w; e[3][2] += w2 * emv.w; e[3][3] += w3 * emv.w;
        }
    }

#pragma unroll
    for (int i = 0; i < 4; ++i) {
        ws[flat0 + i * G * G] = h[i];
#pragma unroll
        for (int c = 0; c < NE; ++c)
            ws[(c + 1) * G3 + flat0 + i * G * G] = e[c][i];
    }
}

// ---------------------------------------------------------------------------
// 3) fused step (leak + alpha*laplacian + relu) + trilinear sample.
//    8-way corner parallelism + shuffle reduction.
//    NOTE reference transpose: splat flattens (c0*G+c1)*G+c2 but sampling
//    reads vol[comp2][comp1][comp0] -> flat = comp2*G^2 + comp1*G + comp0.
// ---------------------------------------------------------------------------
__device__ __forceinline__ float stepped_at(const float* __restrict__ vol,
                                            int z, int y, int x,
                                            float addc, float alpha) {
    const int zm = max(z - 1, 0), zp = min(z + 1, G - 1);
    const int ym = max(y - 1, 0), yp = min(y + 1, G - 1);
    const int xm = max(x - 1, 0), xp = min(x + 1, G - 1);
    const float cv  = vol[(z * G + y) * G + x];
    const float lap = vol[(zm * G + y) * G + x] + vol[(zp * G + y) * G + x]
                    + vol[(z * G + ym) * G + x] + vol[(z * G + yp) * G + x]
                    + vol[(z * G + y) * G + xm] + vol[(z * G + y) * G + xp]
                    - 6.0f * cv;
    const float s = cv * (1.0f - LEAK) + addc + alpha * lap;
    return fmaxf(s, 0.0f);
}

__global__ void __launch_bounds__(256) sample_kernel(
        const float* __restrict__ sp, const float* __restrict__ ws,
        float* __restrict__ out, int n_out) {
    const int gt = blockIdx.x * blockDim.x + threadIdx.x;
    const int corner = gt & 7;
    const int o = gt >> 3;
    if (o >= n_out) return;
    const int c = o % 5;   // 0 = H, 1..4 = E
    const int p = o / 5;

    const float t0 = fminf(fmaxf((sp[p * 3 + 0] + 1.0f) * 0.5f * (float)(G - 1), 0.0f), (float)(G - 1));
    const float t1 = fminf(fmaxf((sp[p * 3 + 1] + 1.0f) * 0.5f * (float)(G - 1), 0.0f), (float)(G - 1));
    const float t2 = fminf(fmaxf((sp[p * 3 + 2] + 1.0f) * 0.5f * (float)(G - 1), 0.0f), (float)(G - 1));

    const int a0 = (int)floorf(t0);  const float f0 = t0 - (float)a0;
    const int a1 = (int)floorf(t1);  const float f1 = t1 - (float)a1;
    const int a2 = (int)floorf(t2);  const float f2 = t2 - (float)a2;
    const int b0 = min(a0 + 1, G - 1);
    const int b1 = min(a1 + 1, G - 1);
    const int b2 = min(a2 + 1, G - 1);

    const int d0 = corner & 1, d1 = (corner >> 1) & 1, d2 = corner >> 2;
    const int   x = d0 ? b0 : a0;          // comp0 -> fastest axis
    const int   y = d1 ? b1 : a1;          // comp1
    const int   z = d2 ? b2 : a2;          // comp2 -> slowest axis
    const float w = (d0 ? f0 : 1.0f - f0) * (d1 ? f1 : 1.0f - f1)
                  * (d2 ? f2 : 1.0f - f2);

    const float* vol  = ws + (size_t)c * G3;
    const float addc  = (c == 0) ? 0.0f : LEAK;
    const float alpha = (c == 0) ? A_H : A_E;

    float v = w * stepped_at(vol, z, y, x, addc, alpha);
    v += __shfl_xor(v, 1);
    v += __shfl_xor(v, 2);
    v += __shfl_xor(v, 4);
    if (corner == 0) out[o] = v;
}

// ---------------------------------------------------------------------------
extern "C" void kernel_launch(void* const* d_in, const int* in_sizes, int n_in,
                              void* d_out, int out_size, void* d_ws, size_t ws_size,
                              hipStream_t stream) {
    const float* positions   = (const float*)d_in[0];  // (N,3)
    const float* intensities = (const float*)d_in[1];  // (N,)
    const float* emotions    = (const float*)d_in[2];  // (N,4)
    const float* sample_pos  = (const float*)d_in[3];  // (B,T,3)
    const float* H0          = (const float*)d_in[4];  // (G,G,G)
    const float* E0          = (const float*)d_in[5];  // (4,G,G,G)
    float* ws  = (float*)d_ws;
    float* out = (float*)d_out;

    const int N = in_sizes[0] / 3;

    int*    counts = (int*)(ws + 5 * (size_t)G3);
    int*    lists  = counts + NTILES;
    float4* meta   = (float4*)(lists + (size_t)NTILES * CAP);

    zero_counts<<<2, 256, 0, stream>>>((int4*)counts);   // 2048 ints

    bin_meta_kernel<<<(N + 3) / 4, 256, 0, stream>>>(
        positions, intensities, (const float4*)emotions, counts, lists, meta, N);

    gather_kernel<<<NTILES, 256, 0, stream>>>(
        meta, H0, E0, counts, lists, ws);

    const int n_thr = out_size * 8;
    sample_kernel<<<(n_thr + 255) / 256, 256, 0, stream>>>(
        sample_pos, ws, out, out_size);
}

// Round 6
// 139.231 us; speedup vs baseline: 1.0225x; 1.0225x over previous
//
#include <hip/hip_runtime.h>

// Terrain3D — gather formulation; fixed-trip unrolled hot loop with
// double-buffered per-particle separable tables in LDS.
// ws layout (floats): [0, 5*G3) = H,E grids; then int counts[NTILES];
// then int lists[NTILES*CAP]; then float4 meta[2*N] ({gx,gy,gz,omega},{m0..m3}).

namespace {
constexpr int   G      = 128;
constexpr int   G3     = G * G * G;
constexpr int   NE     = 4;
constexpr int   RAD    = 9;            // max(2, int(3*0.05*128/2)) = 9
constexpr float SIG    = 0.05f * (float)G * 0.5f;  // 3.2
constexpr float INV2S2 = 1.0f / (2.0f * SIG * SIG);
constexpr float ETA    = 0.01f;
constexpr float A_H    = 0.002f;
constexpr float A_E    = 0.001f;
constexpr float LEAK   = 5e-5f;

// tile geometry: 8 x 8 x 16 voxels. 256 threads; thread owns 4 axis0 voxels
// i = (tid>>7) + {0,2,4,6} at its (j = (tid>>4)&7, k = tid&15).
constexpr int T0 = 8, T1 = 8, T2 = 16;
constexpr int NT0 = G / T0, NT1 = G / T1, NT2 = G / T2;   // 16, 16, 8
constexpr int NTILES = NT0 * NT1 * NT2;                   // 2048
constexpr int CAP   = 128;  // mean particles/tile ~45; max ~80
constexpr int CHUNK = 16;   // particles per table chunk (fixed-trip unroll)
}

__device__ __forceinline__ int clampi(int v, int lo, int hi) {
    return min(max(v, lo), hi);
}

// ---------------------------------------------------------------------------
// 0) zero the tile counts (replaces hipMemsetAsync fill dispatch)
// ---------------------------------------------------------------------------
__global__ void zero_counts(int4* __restrict__ counts4) {
    counts4[threadIdx.x + blockIdx.x * blockDim.x] = make_int4(0, 0, 0, 0);
}

// ---------------------------------------------------------------------------
// 1) bin + meta: one WAVE per particle. Lane 0 writes particle meta; the
//    first 48 lanes cover the 4x4x3 candidate-tile grid of the bbox.
// ---------------------------------------------------------------------------
__global__ void __launch_bounds__(256) bin_meta_kernel(
        const float* __restrict__ pos, const float* __restrict__ inten,
        const float4* __restrict__ emo4,
        int* __restrict__ counts, int* __restrict__ lists,
        float4* __restrict__ meta, int N) {
    const int p    = blockIdx.x * 4 + (threadIdx.x >> 6);
    const int lane = threadIdx.x & 63;
    if (p >= N) return;

    const float gx = (pos[p * 3 + 0] + 1.0f) * 0.5f * (float)(G - 1);
    const float gy = (pos[p * 3 + 1] + 1.0f) * 0.5f * (float)(G - 1);
    const float gz = (pos[p * 3 + 2] + 1.0f) * 0.5f * (float)(G - 1);
    const int c0 = clampi((int)floorf(gx), 0, G - 1);
    const int c1 = clampi((int)floorf(gy), 0, G - 1);
    const int c2 = clampi((int)floorf(gz), 0, G - 1);

    if (lane == 0) {
        meta[2 * p]     = make_float4(gx, gy, gz, inten[p] * ETA);
        meta[2 * p + 1] = emo4[p];
    }

    const int l0 = max(c0 - RAD, 0) >> 3, h0 = min(c0 + RAD, G - 1) >> 3;
    const int l1 = max(c1 - RAD, 0) >> 3, h1 = min(c1 + RAD, G - 1) >> 3;
    const int l2 = max(c2 - RAD, 0) >> 4, h2 = min(c2 + RAD, G - 1) >> 4;
    const int n0 = h0 - l0, n1 = h1 - l1, n2 = h2 - l2;  // inclusive spans - 1

    if (lane < 48) {                    // fixed 4x4x3 slot grid, single pass
        const int a  = lane / 12;       // 0..3
        const int r  = lane - a * 12;
        const int b  = r / 3;           // 0..3
        const int cs = r - b * 3;       // 0..2
        if (a <= n0 && b <= n1 && cs <= n2) {
            const int t = ((l0 + a) * NT1 + (l1 + b)) * NT2 + (l2 + cs);
            const int slot = atomicAdd(&counts[t], 1);
            if (slot < CAP) lists[t * CAP + slot] = p;
        }
    }
}

// ---------------------------------------------------------------------------
// 2) gather: one block per tile. Double-buffered per-particle tables
//    (kx[8] interleaved {iA,t}: slot (i&1)*4+(i>>1), omega folded, validity
//    zeros; ky[8]; kz[16]; em[4]) — 2 x 2304 B. Hot loop: fixed CHUNK trips,
//    fully unrolled; pad slots have kx=0 so their FMAs are no-ops.
// ---------------------------------------------------------------------------
__global__ void __launch_bounds__(256) gather_kernel(
        const float4* __restrict__ meta,
        const float* __restrict__ H0, const float* __restrict__ E0,
        const int* __restrict__ counts, const int* __restrict__ lists,
        float* __restrict__ ws) {
    const int tile = blockIdx.x;
    const int t2 = tile & 7, t1 = (tile >> 3) & 15, t0 = tile >> 7;
    const int tid = threadIdx.x;

    __shared__ __align__(16) float kxf[2][CHUNK * 8];
    __shared__ __align__(16) float emf[2][CHUNK * 4];
    __shared__ float kyf[2][CHUNK * 8];
    __shared__ float kzf[2][CHUNK * 16];

    const int cnt = min(counts[tile], CAP);
    const int* __restrict__ lst = lists + tile * CAP;

    const int b0 = t0 * T0, b1 = t1 * T1, b2 = t2 * T2;

    // ---- per-thread voxels: i = iA + {0,2,4,6} at (j, k) ----
    const int k  = tid & 15;           // axis2
    const int j  = (tid >> 4) & 7;     // axis1
    const int iA = tid >> 7;           // 0/1
    const int x2 = b2 + k, x1 = b1 + j;
    const int flat0 = ((b0 + iA) * G + x1) * G + x2;   // i step = 2*G*G

    float h[4], e[NE][4];
#pragma unroll
    for (int i = 0; i < 4; ++i) {
        h[i] = H0[flat0 + i * 2 * G * G];
#pragma unroll
        for (int c = 0; c < NE; ++c)
            e[c][i] = E0[c * G3 + flat0 + i * 2 * G * G];
    }

    // ---- table builder for one chunk into buffer bb ----
    auto build = [&](int bb, int base) {
        const int m = min(CHUNK, cnt - base);
        for (int t = tid; t < CHUNK * 40; t += 256) {
            const int n = t / 40;
            const int s = t - n * 40;
            if (n < m) {
                const int p = lst[base + n];
                if (s < 32) {
                    const float4 mg = meta[2 * p];
                    int off, tb;
                    float g;
                    if (s < 8)       { off = s;      tb = b0; g = mg.x; }
                    else if (s < 16) { off = s - 8;  tb = b1; g = mg.y; }
                    else             { off = s - 16; tb = b2; g = mg.z; }
                    const int cc    = clampi((int)floorf(g), 0, G - 1);
                    const int coord = tb + off;
                    const float d   = (float)coord - g;
                    float v = (abs(coord - cc) <= RAD)
                            ? __expf(-d * d * INV2S2) : 0.0f;
                    if (s < 8)       kxf[bb][n * 8 + (off & 1) * 4 + (off >> 1)] = v * mg.w;
                    else if (s < 16) kyf[bb][n * 8 + off] = v;
                    else             kzf[bb][n * 16 + off] = v;
                } else if (s < 36) {
                    const float4 me = meta[2 * p + 1];
                    const int q = s - 32;
                    emf[bb][n * 4 + q] = (q == 0) ? me.x : (q == 1) ? me.y
                                       : (q == 2) ? me.z : me.w;
                }
            } else if (s < 8) {
                kxf[bb][n * 8 + s] = 0.0f;   // pad: zero weight kills the FMA
            }
        }
    };

    const int nchunks = (cnt + CHUNK - 1) / CHUNK;
    if (nchunks > 0) build(0, 0);

    for (int c = 0; c < nchunks; ++c) {
        __syncthreads();
        if (c + 1 < nchunks) build((c + 1) & 1, (c + 1) * CHUNK);

        const int bb = c & 1;
        const float4* __restrict__ kx4 = (const float4*)&kxf[bb][0];
        const float4* __restrict__ em4 = (const float4*)&emf[bb][0];
        const float*  __restrict__ kyp = &kyf[bb][0];
        const float*  __restrict__ kzp = &kzf[bb][0];

#pragma unroll
        for (int n = 0; n < CHUNK; ++n) {
            const float4 kxv = kx4[n * 2 + iA];      // ds_read_b128, 2 addrs
            const float4 emv = em4[n];               // ds_read_b128, broadcast
            const float kyz = kyp[n * 8 + j] * kzp[n * 16 + k];
            const float w0 = kxv.x * kyz, w1 = kxv.y * kyz;
            const float w2 = kxv.z * kyz, w3 = kxv.w * kyz;
            h[0] += w0;  h[1] += w1;  h[2] += w2;  h[3] += w3;
            e[0][0] += w0 * emv.x; e[0][1] += w1 * emv.x; e[0][2] += w2 * emv.x; e[0][3] += w3 * emv.x;
            e[1][0] += w0 * emv.y; e[1][1] += w1 * emv.y; e[1][2] += w2 * emv.y; e[1][3] += w3 * emv.y;
            e[2][0] += w0 * emv.z; e[2][1] += w1 * emv.z; e[2][2] += w2 * emv.z; e[2][3] += w3 * emv.z;
            e[3][0] += w0 * emv.w; e[3][1] += w1 * emv.w; e[3][2] += w2 * emv.w; e[3][3] += w3 * emv.w;
        }
    }

#pragma unroll
    for (int i = 0; i < 4; ++i) {
        ws[flat0 + i * 2 * G * G] = h[i];
#pragma unroll
        for (int c = 0; c < NE; ++c)
            ws[(c + 1) * G3 + flat0 + i * 2 * G * G] = e[c][i];
    }
}

// ---------------------------------------------------------------------------
// 3) fused step (leak + alpha*laplacian + relu) + trilinear sample.
//    8-way corner parallelism + shuffle reduction.
//    NOTE reference transpose: splat flattens (c0*G+c1)*G+c2 but sampling
//    reads vol[comp2][comp1][comp0] -> flat = comp2*G^2 + comp1*G + comp0.
// ---------------------------------------------------------------------------
__device__ __forceinline__ float stepped_at(const float* __restrict__ vol,
                                            int z, int y, int x,
                                            float addc, float alpha) {
    const int zm = max(z - 1, 0), zp = min(z + 1, G - 1);
    const int ym = max(y - 1, 0), yp = min(y + 1, G - 1);
    const int xm = max(x - 1, 0), xp = min(x + 1, G - 1);
    const float cv  = vol[(z * G + y) * G + x];
    const float lap = vol[(zm * G + y) * G + x] + vol[(zp * G + y) * G + x]
                    + vol[(z * G + ym) * G + x] + vol[(z * G + yp) * G + x]
                    + vol[(z * G + y) * G + xm] + vol[(z * G + y) * G + xp]
                    - 6.0f * cv;
    const float s = cv * (1.0f - LEAK) + addc + alpha * lap;
    return fmaxf(s, 0.0f);
}

__global__ void __launch_bounds__(256) sample_kernel(
        const float* __restrict__ sp, const float* __restrict__ ws,
        float* __restrict__ out, int n_out) {
    const int gt = blockIdx.x * blockDim.x + threadIdx.x;
    const int corner = gt & 7;
    const int o = gt >> 3;
    if (o >= n_out) return;
    const int c = o % 5;   // 0 = H, 1..4 = E
    const int p = o / 5;

    const float t0 = fminf(fmaxf((sp[p * 3 + 0] + 1.0f) * 0.5f * (float)(G - 1), 0.0f), (float)(G - 1));
    const float t1 = fminf(fmaxf((sp[p * 3 + 1] + 1.0f) * 0.5f * (float)(G - 1), 0.0f), (float)(G - 1));
    const float t2 = fminf(fmaxf((sp[p * 3 + 2] + 1.0f) * 0.5f * (float)(G - 1), 0.0f), (float)(G - 1));

    const int a0 = (int)floorf(t0);  const float f0 = t0 - (float)a0;
    const int a1 = (int)floorf(t1);  const float f1 = t1 - (float)a1;
    const int a2 = (int)floorf(t2);  const float f2 = t2 - (float)a2;
    const int b0 = min(a0 + 1, G - 1);
    const int b1 = min(a1 + 1, G - 1);
    const int b2 = min(a2 + 1, G - 1);

    const int d0 = corner & 1, d1 = (corner >> 1) & 1, d2 = corner >> 2;
    const int   x = d0 ? b0 : a0;          // comp0 -> fastest axis
    const int   y = d1 ? b1 : a1;          // comp1
    const int   z = d2 ? b2 : a2;          // comp2 -> slowest axis
    const float w = (d0 ? f0 : 1.0f - f0) * (d1 ? f1 : 1.0f - f1)
                  * (d2 ? f2 : 1.0f - f2);

    const float* vol  = ws + (size_t)c * G3;
    const float addc  = (c == 0) ? 0.0f : LEAK;
    const float alpha = (c == 0) ? A_H : A_E;

    float v = w * stepped_at(vol, z, y, x, addc, alpha);
    v += __shfl_xor(v, 1);
    v += __shfl_xor(v, 2);
    v += __shfl_xor(v, 4);
    if (corner == 0) out[o] = v;
}

// ---------------------------------------------------------------------------
extern "C" void kernel_launch(void* const* d_in, const int* in_sizes, int n_in,
                              void* d_out, int out_size, void* d_ws, size_t ws_size,
                              hipStream_t stream) {
    const float* positions   = (const float*)d_in[0];  // (N,3)
    const float* intensities = (const float*)d_in[1];  // (N,)
    const float* emotions    = (const float*)d_in[2];  // (N,4)
    const float* sample_pos  = (const float*)d_in[3];  // (B,T,3)
    const float* H0          = (const float*)d_in[4];  // (G,G,G)
    const float* E0          = (const float*)d_in[5];  // (4,G,G,G)
    float* ws  = (float*)d_ws;
    float* out = (float*)d_out;

    const int N = in_sizes[0] / 3;

    int*    counts = (int*)(ws + 5 * (size_t)G3);
    int*    lists  = counts + NTILES;
    float4* meta   = (float4*)(lists + (size_t)NTILES * CAP);

    zero_counts<<<2, 256, 0, stream>>>((int4*)counts);   // 2048 ints

    bin_meta_kernel<<<(N + 3) / 4, 256, 0, stream>>>(
        positions, intensities, (const float4*)emotions, counts, lists, meta, N);

    gather_kernel<<<NTILES, 256, 0, stream>>>(
        meta, H0, E0, counts, lists, ws);

    const int n_thr = out_size * 8;
    sample_kernel<<<(n_thr + 255) / 256, 256, 0, stream>>>(
        sample_pos, ws, out, out_size);
}

// Round 7
// 135.315 us; speedup vs baseline: 1.0521x; 1.0289x over previous
//
#include <hip/hip_runtime.h>

// Terrain3D — gather formulation; one-shot per-particle tables (thread n owns
// particle n), single barrier, LDS-only fully-unrolled consume loop.
// ws layout (floats): [0, 5*G3) = H,E grids; then int counts[NTILES];
// then int lists[NTILES*CAP]; then float4 meta[2*N] ({gx,gy,gz,omega},{m0..m3}).

namespace {
constexpr int   G      = 128;
constexpr int   G3     = G * G * G;
constexpr int   NE     = 4;
constexpr int   RAD    = 9;            // max(2, int(3*0.05*128/2)) = 9
constexpr float SIG    = 0.05f * (float)G * 0.5f;  // 3.2
constexpr float INV2S2 = 1.0f / (2.0f * SIG * SIG);
constexpr float ETA    = 0.01f;
constexpr float A_H    = 0.002f;
constexpr float A_E    = 0.001f;
constexpr float LEAK   = 5e-5f;

// tile geometry: 8 x 8 x 16 voxels. 256 threads; thread owns 4 axis0 voxels
// i = (tid>>7) + {0,2,4,6} at its (j = (tid>>4)&7, k = tid&15).
constexpr int T0 = 8, T1 = 8, T2 = 16;
constexpr int NT0 = G / T0, NT1 = G / T1, NT2 = G / T2;   // 16, 16, 8
constexpr int NTILES = NT0 * NT1 * NT2;                   // 2048
constexpr int CAP  = 112;  // mean particles/tile ~52; P(>112) ~ 0
constexpr int CPAD = 113;  // SoA stride for ky/kz (odd -> conflict-free)
}

__device__ __forceinline__ int clampi(int v, int lo, int hi) {
    return min(max(v, lo), hi);
}

// ---------------------------------------------------------------------------
// 0) zero the tile counts (replaces hipMemsetAsync fill dispatch)
// ---------------------------------------------------------------------------
__global__ void zero_counts(int4* __restrict__ counts4) {
    counts4[threadIdx.x + blockIdx.x * blockDim.x] = make_int4(0, 0, 0, 0);
}

// ---------------------------------------------------------------------------
// 1) bin + meta: one WAVE per particle. Lane 0 writes particle meta; the
//    first 48 lanes cover the 4x4x3 candidate-tile grid of the bbox.
// ---------------------------------------------------------------------------
__global__ void __launch_bounds__(256) bin_meta_kernel(
        const float* __restrict__ pos, const float* __restrict__ inten,
        const float4* __restrict__ emo4,
        int* __restrict__ counts, int* __restrict__ lists,
        float4* __restrict__ meta, int N) {
    const int p    = blockIdx.x * 4 + (threadIdx.x >> 6);
    const int lane = threadIdx.x & 63;
    if (p >= N) return;

    const float gx = (pos[p * 3 + 0] + 1.0f) * 0.5f * (float)(G - 1);
    const float gy = (pos[p * 3 + 1] + 1.0f) * 0.5f * (float)(G - 1);
    const float gz = (pos[p * 3 + 2] + 1.0f) * 0.5f * (float)(G - 1);
    const int c0 = clampi((int)floorf(gx), 0, G - 1);
    const int c1 = clampi((int)floorf(gy), 0, G - 1);
    const int c2 = clampi((int)floorf(gz), 0, G - 1);

    if (lane == 0) {
        meta[2 * p]     = make_float4(gx, gy, gz, inten[p] * ETA);
        meta[2 * p + 1] = emo4[p];
    }

    const int l0 = max(c0 - RAD, 0) >> 3, h0 = min(c0 + RAD, G - 1) >> 3;
    const int l1 = max(c1 - RAD, 0) >> 3, h1 = min(c1 + RAD, G - 1) >> 3;
    const int l2 = max(c2 - RAD, 0) >> 4, h2 = min(c2 + RAD, G - 1) >> 4;
    const int n0 = h0 - l0, n1 = h1 - l1, n2 = h2 - l2;  // inclusive spans - 1

    if (lane < 48) {                    // fixed 4x4x3 slot grid, single pass
        const int a  = lane / 12;       // 0..3
        const int r  = lane - a * 12;
        const int b  = r / 3;           // 0..3
        const int cs = r - b * 3;       // 0..2
        if (a <= n0 && b <= n1 && cs <= n2) {
            const int t = ((l0 + a) * NT1 + (l1 + b)) * NT2 + (l2 + cs);
            const int slot = atomicAdd(&counts[t], 1);
            if (slot < CAP) lists[t * CAP + slot] = p;
        }
    }
}

// ---------------------------------------------------------------------------
// 2) gather: one block per tile. Phase 1: thread n (< padded cnt) builds the
//    full separable table for particle n — one parallel meta load round-trip
//    per block, independent exps, pad slots get kx=0. ONE barrier. Phase 2:
//    fixed-unroll consume touching only LDS (kx/em AoS float4 broadcast,
//    ky/kz SoA stride-113 conflict-free): ~25 VALU for 20 accumulators.
// ---------------------------------------------------------------------------
__global__ void __launch_bounds__(256) gather_kernel(
        const float4* __restrict__ meta,
        const float* __restrict__ H0, const float* __restrict__ E0,
        const int* __restrict__ counts, const int* __restrict__ lists,
        float* __restrict__ ws) {
    const int tile = blockIdx.x;
    const int t2 = tile & 7, t1 = (tile >> 3) & 15, t0 = tile >> 7;
    const int tid = threadIdx.x;

    __shared__ __align__(16) float kxf[CAP * 8];   // AoS: n*8 + iA*4 + ii
    __shared__ __align__(16) float emf[CAP * 4];   // AoS: n*4 + c
    __shared__ float kyf[8 * CPAD];                // SoA: off*CPAD + n
    __shared__ float kzf[16 * CPAD];               // SoA: off*CPAD + n

    const int b0 = t0 * T0, b1 = t1 * T1, b2 = t2 * T2;

    // ---- per-thread voxels: i = iA + {0,2,4,6} at (j, k) ----
    const int k  = tid & 15;           // axis2
    const int j  = (tid >> 4) & 7;     // axis1
    const int iA = tid >> 7;           // 0/1
    const int x2 = b2 + k, x1 = b1 + j;
    const int flat0 = ((b0 + iA) * G + x1) * G + x2;   // i step = 2*G*G

    // issue init loads FIRST — latency hides under phase 1
    float h[4], e[NE][4];
#pragma unroll
    for (int i = 0; i < 4; ++i) {
        h[i] = H0[flat0 + i * 2 * G * G];
#pragma unroll
        for (int c = 0; c < NE; ++c)
            e[c][i] = E0[c * G3 + flat0 + i * 2 * G * G];
    }

    const int cnt    = min(counts[tile], CAP);
    const int padded = (cnt + 15) & ~15;

    // ---- phase 1: thread n builds particle n's table ----
    if (tid < padded) {
        float4* kx4w = (float4*)kxf;
        if (tid < cnt) {
            const int p = lists[tile * CAP + tid];
            const float4 mg = meta[2 * p];
            const float4 me = meta[2 * p + 1];
            const int cx = clampi((int)floorf(mg.x), 0, G - 1);
            const int cy = clampi((int)floorf(mg.y), 0, G - 1);
            const int cz = clampi((int)floorf(mg.z), 0, G - 1);

            float4 kxa, kxb;
            {
                float* a = &kxa.x;
                float* b = &kxb.x;
#pragma unroll
                for (int ii = 0; ii < 4; ++ii) {
                    const int c0a = b0 + 2 * ii;       // iA = 0
                    const int c0b = b0 + 1 + 2 * ii;   // iA = 1
                    const float da = (float)c0a - mg.x;
                    const float db = (float)c0b - mg.x;
                    a[ii] = (abs(c0a - cx) <= RAD)
                          ? __expf(-da * da * INV2S2) * mg.w : 0.0f;
                    b[ii] = (abs(c0b - cx) <= RAD)
                          ? __expf(-db * db * INV2S2) * mg.w : 0.0f;
                }
            }
            kx4w[tid * 2 + 0] = kxa;
            kx4w[tid * 2 + 1] = kxb;

#pragma unroll
            for (int off = 0; off < 8; ++off) {
                const int coord = b1 + off;
                const float d = (float)coord - mg.y;
                kyf[off * CPAD + tid] = (abs(coord - cy) <= RAD)
                                      ? __expf(-d * d * INV2S2) : 0.0f;
            }
#pragma unroll
            for (int off = 0; off < 16; ++off) {
                const int coord = b2 + off;
                const float d = (float)coord - mg.z;
                kzf[off * CPAD + tid] = (abs(coord - cz) <= RAD)
                                      ? __expf(-d * d * INV2S2) : 0.0f;
            }
            ((float4*)emf)[tid] = me;
        } else {
            const float4 z4 = make_float4(0.f, 0.f, 0.f, 0.f);
            kx4w[tid * 2 + 0] = z4;    // zero weight kills pad FMAs
            kx4w[tid * 2 + 1] = z4;
        }
    }
    __syncthreads();

    // ---- phase 2: LDS-only unrolled consume ----
    const float4* __restrict__ kx4 = (const float4*)kxf;
    const float4* __restrict__ em4 = (const float4*)emf;
    const float*  __restrict__ kyp = kyf + j * CPAD;
    const float*  __restrict__ kzp = kzf + k * CPAD;

    for (int base = 0; base < padded; base += 16) {
#pragma unroll
        for (int u = 0; u < 16; ++u) {
            const int n = base + u;
            const float4 kxv = kx4[n * 2 + iA];   // b128, wave-uniform addr
            const float4 emv = em4[n];            // b128, broadcast
            const float kyz = kyp[n] * kzp[n];    // 2x b32, conflict-free
            const float w0 = kxv.x * kyz, w1 = kxv.y * kyz;
            const float w2 = kxv.z * kyz, w3 = kxv.w * kyz;
            h[0] += w0;  h[1] += w1;  h[2] += w2;  h[3] += w3;
            e[0][0] += w0 * emv.x; e[0][1] += w1 * emv.x; e[0][2] += w2 * emv.x; e[0][3] += w3 * emv.x;
            e[1][0] += w0 * emv.y; e[1][1] += w1 * emv.y; e[1][2] += w2 * emv.y; e[1][3] += w3 * emv.y;
            e[2][0] += w0 * emv.z; e[2][1] += w1 * emv.z; e[2][2] += w2 * emv.z; e[2][3] += w3 * emv.z;
            e[3][0] += w0 * emv.w; e[3][1] += w1 * emv.w; e[3][2] += w2 * emv.w; e[3][3] += w3 * emv.w;
        }
    }

#pragma unroll
    for (int i = 0; i < 4; ++i) {
        ws[flat0 + i * 2 * G * G] = h[i];
#pragma unroll
        for (int c = 0; c < NE; ++c)
            ws[(c + 1) * G3 + flat0 + i * 2 * G * G] = e[c][i];
    }
}

// ---------------------------------------------------------------------------
// 3) fused step (leak + alpha*laplacian + relu) + trilinear sample.
//    8-way corner parallelism + shuffle reduction.
//    NOTE reference transpose: splat flattens (c0*G+c1)*G+c2 but sampling
//    reads vol[comp2][comp1][comp0] -> flat = comp2*G^2 + comp1*G + comp0.
// ---------------------------------------------------------------------------
__device__ __forceinline__ float stepped_at(const float* __restrict__ vol,
                                            int z, int y, int x,
                                            float addc, float alpha) {
    const int zm = max(z - 1, 0), zp = min(z + 1, G - 1);
    const int ym = max(y - 1, 0), yp = min(y + 1, G - 1);
    const int xm = max(x - 1, 0), xp = min(x + 1, G - 1);
    const float cv  = vol[(z * G + y) * G + x];
    const float lap = vol[(zm * G + y) * G + x] + vol[(zp * G + y) * G + x]
                    + vol[(z * G + ym) * G + x] + vol[(z * G + yp) * G + x]
                    + vol[(z * G + y) * G + xm] + vol[(z * G + y) * G + xp]
                    - 6.0f * cv;
    const float s = cv * (1.0f - LEAK) + addc + alpha * lap;
    return fmaxf(s, 0.0f);
}

__global__ void __launch_bounds__(256) sample_kernel(
        const float* __restrict__ sp, const float* __restrict__ ws,
        float* __restrict__ out, int n_out) {
    const int gt = blockIdx.x * blockDim.x + threadIdx.x;
    const int corner = gt & 7;
    const int o = gt >> 3;
    if (o >= n_out) return;
    const int c = o % 5;   // 0 = H, 1..4 = E
    const int p = o / 5;

    const float t0 = fminf(fmaxf((sp[p * 3 + 0] + 1.0f) * 0.5f * (float)(G - 1), 0.0f), (float)(G - 1));
    const float t1 = fminf(fmaxf((sp[p * 3 + 1] + 1.0f) * 0.5f * (float)(G - 1), 0.0f), (float)(G - 1));
    const float t2 = fminf(fmaxf((sp[p * 3 + 2] + 1.0f) * 0.5f * (float)(G - 1), 0.0f), (float)(G - 1));

    const int a0 = (int)floorf(t0);  const float f0 = t0 - (float)a0;
    const int a1 = (int)floorf(t1);  const float f1 = t1 - (float)a1;
    const int a2 = (int)floorf(t2);  const float f2 = t2 - (float)a2;
    const int b0 = min(a0 + 1, G - 1);
    const int b1 = min(a1 + 1, G - 1);
    const int b2 = min(a2 + 1, G - 1);

    const int d0 = corner & 1, d1 = (corner >> 1) & 1, d2 = corner >> 2;
    const int   x = d0 ? b0 : a0;          // comp0 -> fastest axis
    const int   y = d1 ? b1 : a1;          // comp1
    const int   z = d2 ? b2 : a2;          // comp2 -> slowest axis
    const float w = (d0 ? f0 : 1.0f - f0) * (d1 ? f1 : 1.0f - f1)
                  * (d2 ? f2 : 1.0f - f2);

    const float* vol  = ws + (size_t)c * G3;
    const float addc  = (c == 0) ? 0.0f : LEAK;
    const float alpha = (c == 0) ? A_H : A_E;

    float v = w * stepped_at(vol, z, y, x, addc, alpha);
    v += __shfl_xor(v, 1);
    v += __shfl_xor(v, 2);
    v += __shfl_xor(v, 4);
    if (corner == 0) out[o] = v;
}

// ---------------------------------------------------------------------------
extern "C" void kernel_launch(void* const* d_in, const int* in_sizes, int n_in,
                              void* d_out, int out_size, void* d_ws, size_t ws_size,
                              hipStream_t stream) {
    const float* positions   = (const float*)d_in[0];  // (N,3)
    const float* intensities = (const float*)d_in[1];  // (N,)
    const float* emotions    = (const float*)d_in[2];  // (N,4)
    const float* sample_pos  = (const float*)d_in[3];  // (B,T,3)
    const float* H0          = (const float*)d_in[4];  // (G,G,G)
    const float* E0          = (const float*)d_in[5];  // (4,G,G,G)
    float* ws  = (float*)d_ws;
    float* out = (float*)d_out;

    const int N = in_sizes[0] / 3;

    int*    counts = (int*)(ws + 5 * (size_t)G3);
    int*    lists  = counts + NTILES;
    float4* meta   = (float4*)(lists + (size_t)NTILES * CAP);

    zero_counts<<<2, 256, 0, stream>>>((int4*)counts);   // 2048 ints

    bin_meta_kernel<<<(N + 3) / 4, 256, 0, stream>>>(
        positions, intensities, (const float4*)emotions, counts, lists, meta, N);

    gather_kernel<<<NTILES, 256, 0, stream>>>(
        meta, H0, E0, counts, lists, ws);

    const int n_thr = out_size * 8;
    sample_kernel<<<(n_thr + 255) / 256, 256, 0, stream>>>(
        sample_pos, ws, out, out_size);
}